// Round 18
// baseline (3271.259 us; speedup 1.0000x reference)
//
#include <hip/hip_runtime.h>
#include <hip/hip_cooperative_groups.h>

namespace cg = cooperative_groups;

#define BBAT 32
#define SE 200
#define TT 400
#define MM 80
#define EE 512
#define HH 1024
#define IN0 592
#define KS 608         // static panel row: x(80) + ctx(512) + zero pad(16)
#define NSC 19         // static chunks (KS/32)
#define W0S 1640       // W0 LDS row stride (608 static + 1024 hh + 8 pad)
#define W1STR 1032
#define NBLK 256
#define NTHR 512

typedef __attribute__((ext_vector_type(4))) float f32x4;
typedef __attribute__((ext_vector_type(8))) short s16x8;
typedef unsigned long long u64;

// LDS offsets (bytes)
#define OFF_W0    0          // 16*1640*2 = 52480
#define OFF_W1I   52480      // 33024
#define OFF_W1H   85504      // 33024
#define OFF_GRED  118528     // 8 waves x 1024 f32 = 32768 (2 planes)
#define OFF_C0    151296     // 512
#define OFF_C1    151808     // 512
#define OFF_BS    152320     // b0s[16] + b1s[16] f32 = 128
#define LDS_TOTAL 152448
// prologue-only smw/red alias the GRED region (no temporal overlap)

// ws offsets (bytes)
// h0b: [2 parity][32 chunk][32 batch][32 elem] bf16
// h1h: [401 slot][32 chunk][32 batch][32 elem] bf16 write-once history
//      slot t+1 = h1(t); slot 0 = zeros (h1(-1))
#define WS_XSTAT 0                 // 400*32*608*2 = 15,564,800
#define WS_H0B   15564800          // 131,072
#define WS_H1H   15695872          // 401*65536 = 26,279,936
#define WS_ESC   41975808          // 25,600
#define WS_CST   42001408          // 131,072 (cm | cs)
#define WS_FLG   42132480          // dataflow flags: 2*(TT+1)*32 x 16B = 410,624
// flag layout (u32 units): h0 epoch t chunk c -> flg[(t*32+c)*4]
//                          h1 epoch t chunk c -> flg[H1OFFU + (t*32+c)*4]
#define H1OFFU   ((TT+1)*32*4)
#define FLGN     (2*(TT+1)*32*4)

__device__ __forceinline__ float sigmf(float x){ return 1.0f/(1.0f+expf(-x)); }

__device__ __forceinline__ unsigned short f2bf(float v){
  unsigned int u = __float_as_uint(v);
  u += 0x7fffu + ((u >> 16) & 1u);
  return (unsigned short)(u >> 16);
}
__device__ __forceinline__ float bf2f(unsigned short s){
  return __uint_as_float(((unsigned)s) << 16);
}

// ---- agent-scope coherent accessors; RELAXED => no cache-maintenance ops ----
__device__ __forceinline__ void st64a(void* p, u64 v){
  __hip_atomic_store((u64*)p, v, __ATOMIC_RELAXED, __HIP_MEMORY_SCOPE_AGENT);
}

// 4x 16B coherent loads (sc0 sc1 -> coherence point). Chunk-major: each wave
// spans 1KB contiguous per instruction (8x128B lines).
#define LD4C(d0,d1,d2,d3,p0,p1,p2,p3) \
  asm volatile("global_load_dwordx4 %0, %4, off sc0 sc1\n\t" \
               "global_load_dwordx4 %1, %5, off sc0 sc1\n\t" \
               "global_load_dwordx4 %2, %6, off sc0 sc1\n\t" \
               "global_load_dwordx4 %3, %7, off sc0 sc1" \
               : "=&v"(d0), "=&v"(d1), "=&v"(d2), "=&v"(d3) \
               : "v"(p0), "v"(p1), "v"(p2), "v"(p3))

// Single waitcnt tying all 16 fragments as in-outs (anti-hoist: rule #18).
#define WAIT16(a0,a1,a2,a3,b0,b1,b2,b3,c0,c1,c2,c3,d0,d1,d2,d3) \
  asm volatile("s_waitcnt vmcnt(0)" \
    : "+v"(a0),"+v"(a1),"+v"(a2),"+v"(a3), \
      "+v"(b0),"+v"(b1),"+v"(b2),"+v"(b3), \
      "+v"(c0),"+v"(c1),"+v"(c2),"+v"(c3), \
      "+v"(d0),"+v"(d1),"+v"(d2),"+v"(d3))

__device__ __forceinline__ float bsum(float v, float* red){
  #pragma unroll
  for (int o = 32; o; o >>= 1) v += __shfl_down(v, o);
  __syncthreads();
  if ((threadIdx.x & 63) == 0) red[threadIdx.x >> 6] = v;
  __syncthreads();
  float s = 0.f;
  #pragma unroll
  for (int w2 = 0; w2 < 8; ++w2) s += red[w2];
  return s;
}
__device__ __forceinline__ float bmax(float v, float* red){
  #pragma unroll
  for (int o = 32; o; o >>= 1) v = fmaxf(v, __shfl_down(v, o));
  __syncthreads();
  if ((threadIdx.x & 63) == 0) red[threadIdx.x >> 6] = v;
  __syncthreads();
  float s = -3.4e38f;
  #pragma unroll
  for (int w2 = 0; w2 < 8; ++w2) s = fmaxf(s, red[w2]);
  return s;
}

#define MFMA16(a,b,c) __builtin_amdgcn_mfma_f32_16x16x32_bf16((a),(b),(c),0,0,0)

// static-panel MFMAs for LSTM0 time tau (cached loads; xstat stable after prologue)
__device__ __forceinline__ void mfma_static(const unsigned short* __restrict__ xs,
    const unsigned short* __restrict__ W0, int w, int row, int kg,
    f32x4& acc0, f32x4& acc1)
{
  for (int c = w; c < NSC; c += 8) {
    const int off = (c << 5) + (kg << 3);
    s16x8 a0 = *(const s16x8*)(xs + (size_t)row*KS + off);
    s16x8 a1 = *(const s16x8*)(xs + (size_t)(row+16)*KS + off);
    s16x8 bw = *(const s16x8*)(W0 + row*W0S + off);
    acc0 = MFMA16(a0, bw, acc0);
    acc1 = MFMA16(a1, bw, acc1);
  }
}

__global__ void __launch_bounds__(NTHR, 1) decoder_kernel(
    const float* __restrict__ enc, const float* __restrict__ audio,
    const float* __restrict__ Wih0, const float* __restrict__ Whh0,
    const float* __restrict__ bih0, const float* __restrict__ bhh0,
    const float* __restrict__ Wih1, const float* __restrict__ Whh1,
    const float* __restrict__ bih1, const float* __restrict__ bhh1,
    const float* __restrict__ Wa, const float* __restrict__ ba,
    const float* __restrict__ Wfc, const float* __restrict__ bfc,
    float* __restrict__ out, float* __restrict__ ws)
{
  cg::grid_group grid = cg::this_grid();
  extern __shared__ char lds[];
  unsigned short* W0  = (unsigned short*)(lds + OFF_W0);
  unsigned short* W1I = (unsigned short*)(lds + OFF_W1I);
  unsigned short* W1H = (unsigned short*)(lds + OFF_W1H);
  float* Gred = (float*)(lds + OFF_GRED);
  float* c0l  = (float*)(lds + OFF_C0);
  float* c1l  = (float*)(lds + OFF_C1);
  float* b0s  = (float*)(lds + OFF_BS);      // combined LSTM0 biases [p*4+g]
  float* b1s  = b0s + 16;                    // combined LSTM1 biases
  float* smw  = Gred;                        // prologue-only aliases
  float* red  = Gred + 256;

  const int blk = blockIdx.x, tid = threadIdx.x;
  const int j = blk;                                // owns h-columns [4j, 4j+4)
  const int w = tid >> 6, lane = tid & 63;
  const int row = lane & 15, kg = lane >> 4;
  const int cblk = j >> 3;                          // chunk holding this block's cols
  const int colw = (j & 7) << 2;                    // col offset within chunk
  const int eg = tid & 3, ep = (tid >> 2) & 3, eb = tid >> 4;

  unsigned short* xstat = (unsigned short*)((char*)ws + WS_XSTAT);
  unsigned short* h0b   = (unsigned short*)((char*)ws + WS_H0B);   // chunk-major, 2-deep
  unsigned short* h1h   = (unsigned short*)((char*)ws + WS_H1H);   // write-once history
  float* esc  = (float*)((char*)ws + WS_ESC);
  float* cm   = (float*)((char*)ws + WS_CST);
  float* cs   = cm + BBAT*EE;
  unsigned* flg = (unsigned*)((char*)ws + WS_FLG);  // dataflow flags

  // ---- prologue: weights -> LDS bf16; combined biases ----
  for (int i = tid; i < 16*W0S; i += NTHR) {
    int r = i / W0S, k = i - r*W0S;
    int n = (r & 3)*HH + 4*j + (r >> 2);
    float v = 0.f;
    if (k < IN0) v = Wih0[(size_t)n*IN0 + k];
    else if (k >= KS && k < KS + HH) v = Whh0[(size_t)n*HH + (k - KS)];
    W0[i] = f2bf(v);
  }
  for (int i = tid; i < 16*W1STR; i += NTHR) {
    int r = i / W1STR, k = i - r*W1STR;
    int n = (r & 3)*HH + 4*j + (r >> 2);
    W1I[i] = (k < HH) ? f2bf(Wih1[(size_t)n*HH + k]) : (unsigned short)0;
    W1H[i] = (k < HH) ? f2bf(Whh1[(size_t)n*HH + k]) : (unsigned short)0;
  }
  if (tid < 16) {
    int p = tid >> 2, g = tid & 3, n = g*HH + 4*j + p;
    b0s[tid] = bih0[n] + bhh0[n];
    b1s[tid] = bih1[n] + bhh1[n];
  }
  if (tid < 128) { c0l[tid] = 0.f; c1l[tid] = 0.f; }
  for (int i = blk*NTHR + tid; i < 2*BBAT*HH; i += NBLK*NTHR) h0b[i] = 0;
  for (int i = blk*NTHR + tid; i < BBAT*HH; i += NBLK*NTHR) h1h[i] = 0;  // slot 0 = h1(-1)
  for (int i = blk*NTHR + tid; i < FLGN; i += NBLK*NTHR) flg[i] = 0u;
  for (int r2 = blk; r2 < BBAT*SE; r2 += NBLK) {
    float pp = tanhf(enc[(size_t)r2*EE + tid]) * Wa[HH + tid];   // EE == NTHR
    pp = bsum(pp, red);
    if (tid == 0) esc[r2] = pp;
  }
  grid.sync();

  // ---- static softmax + contexts (softmax is h1-invariant; R10-R17 validated) ----
  if (blk < BBAT) {
    const int b = blk;
    float sc = (tid < SE) ? esc[b*SE + tid] : -3.4e38f;
    float mx = bmax(sc, red);
    float ex = (tid < SE) ? expf(sc - mx) : 0.f;
    float den = bsum(ex, red);
    if (tid < SE) smw[tid] = ex / den;
    __syncthreads();
    const int e = tid;                                // EE == NTHR
    float as = 0.f, am = 0.f;
    for (int s = 0; s < SE; ++s) {
      float v = enc[((size_t)b*SE + s)*EE + e];
      as = fmaf(smw[s], v, as);
      am += v;
    }
    cm[b*EE + e] = am * (1.0f/(float)SE);
    cs[b*EE + e] = as;
  }
  grid.sync();

  // ---- fill static panel xstat[t][b][608] = [x_t | ctx | 0] bf16 ----
  for (int t2 = blk; t2 < TT; t2 += NBLK) {
    const float* cx = (t2 == 0) ? cm : cs;
    for (int b = 0; b < BBAT; ++b) {
      for (int k = tid; k < KS; k += NTHR) {
        float v;
        if (k < MM)        v = audio[((size_t)b*TT + t2)*MM + k];
        else if (k < IN0)  v = cx[b*EE + (k - MM)];
        else               v = 0.f;
        xstat[((size_t)t2*BBAT + b)*KS + k] = f2bf(v);
      }
    }
  }
  grid.sync();   // covers flag zeroing + xstat + initial h-buffers

  const f32x4 z4 = {0.f,0.f,0.f,0.f};
  f32x4 accP0 = z4, accP1 = z4;

  // ---- pre-loop: LSTM0(0) = static(0) (h0(-1)=0); publish h0(0) + flag ----
  mfma_static(xstat, W0, w, row, kg, accP0, accP1);
  {
    float* gw = Gred + (w << 10) + row;
    #pragma unroll
    for (int v = 0; v < 4; ++v) {
      gw[(((kg<<2)+v)    << 4)] = accP0[v];
      gw[(((kg<<2)+v+16) << 4)] = accP1[v];
    }
    __syncthreads();
    float s0 = 0.f;
    #pragma unroll
    for (int w8 = 0; w8 < 8; ++w8) s0 += Gred[(w8 << 10) + tid];
    float ga = s0;
    float gb = __shfl_xor(s0, 1);
    float gc = __shfl_xor(s0, 2);
    float gd = __shfl_xor(gb, 2);
    if (eg == 0) {
      f32x4 bi = *(const f32x4*)(b0s + (ep << 2));
      float gi = ga + bi[0], gg = gc + bi[2], go = gd + bi[3];
      (void)gb;
      float cn = sigmf(gi) * tanhf(gg);   // c_old = 0
      c0l[ep*32 + eb] = cn;
      float hn = sigmf(go) * tanhf(cn);
      float hB = __shfl_xor(hn, 4);
      float hC = __shfl_xor(hn, 8);
      float hD = __shfl_xor(hB, 8);
      if ((tid & 15) == 0) {
        u64 hp = (u64)f2bf(hn) | ((u64)f2bf(hB) << 16) | ((u64)f2bf(hC) << 32) | ((u64)f2bf(hD) << 48);
        st64a(h0b + (cblk << 10) + (eb << 5) + colw, hp);   // h0(0) -> parity buf 0
      }
    }
  }
  __builtin_amdgcn_s_waitcnt(0);
  __syncthreads();
  if (tid == 0)
    __hip_atomic_fetch_add(flg + (size_t)cblk*4, 1u, __ATOMIC_RELAXED, __HIP_MEMORY_SCOPE_AGENT);
  accP0 = z4; accP1 = z4;
  mfma_static(xstat + (size_t)BBAT*KS, W0, w, row, kg, accP0, accP1);  // static(1)

  for (int t = 0; t < TT; ++t) {
    const unsigned short* h0R = h0b + (t&1)*BBAT*HH;               // h0(t)
    const unsigned short* h1R = h1h + (size_t)t*BBAT*HH;           // h1(t-1) slot t
    unsigned short* h1W = h1h + (size_t)(t+1)*BBAT*HH;             // h1(t) slot t+1
    unsigned short* h0Wn = h0b + ((t+1)&1)*BBAT*HH;                // h0(t+1)

    // ===== per-wave dataflow poll: wave w needs chunks {w,w+8,w+16,w+24} =====
    {
      const int pc = w + ((lane & 3) << 3);
      if (lane < 4) {
        unsigned* fp = flg + ((size_t)t*32 + pc)*4;
        while (__hip_atomic_load(fp, __ATOMIC_RELAXED, __HIP_MEMORY_SCOPE_AGENT) < 8u)
          __builtin_amdgcn_s_sleep(1);
      } else if (lane < 8 && t > 0) {
        unsigned* fp = flg + H1OFFU + ((size_t)(t-1)*32 + pc)*4;
        while (__hip_atomic_load(fp, __ATOMIC_RELAXED, __HIP_MEMORY_SCOPE_AGENT) < 8u)
          __builtin_amdgcn_s_sleep(1);
      }
      asm volatile("" ::: "memory");   // loads below must not hoist above polls
    }

    // ===== coalesced coherent loads, 40 MFMA, reduce, shfl epilogues =====
    s16x8 A0h[4], A1h[4], A0g[4], A1g[4];
    {
      const unsigned short* ph0a  = h0R + (row << 5) + (kg << 3);
      const unsigned short* ph0b_ = h0R + ((row+16) << 5) + (kg << 3);
      const unsigned short* ph1a  = h1R + (row << 5) + (kg << 3);
      const unsigned short* ph1b_ = h1R + ((row+16) << 5) + (kg << 3);
      const int o0 = (w << 10), o1 = ((w+8) << 10), o2_ = ((w+16) << 10), o3 = ((w+24) << 10);
      LD4C(A0h[0],A0h[1],A0h[2],A0h[3], ph0a+o0, ph0a+o1, ph0a+o2_, ph0a+o3);
      LD4C(A1h[0],A1h[1],A1h[2],A1h[3], ph0b_+o0, ph0b_+o1, ph0b_+o2_, ph0b_+o3);
      LD4C(A0g[0],A0g[1],A0g[2],A0g[3], ph1a+o0, ph1a+o1, ph1a+o2_, ph1a+o3);
      LD4C(A1g[0],A1g[1],A1g[2],A1g[3], ph1b_+o0, ph1b_+o1, ph1b_+o2_, ph1b_+o3);
      WAIT16(A0h[0],A0h[1],A0h[2],A0h[3], A1h[0],A1h[1],A1h[2],A1h[3],
             A0g[0],A0g[1],A0g[2],A0g[3], A1g[0],A1g[1],A1g[2],A1g[3]);
    }
    f32x4 q0 = z4, q1 = z4;
    #pragma unroll
    for (int i = 0; i < 4; ++i) {
      const int off = ((w + (i << 3)) << 5) + (kg << 3);
      s16x8 b1 = *(const s16x8*)(W1I + row*W1STR + off);
      q0 = MFMA16(A0h[i], b1, q0);
      q1 = MFMA16(A1h[i], b1, q1);
      s16x8 b0 = *(const s16x8*)(W0 + row*W0S + KS + off);
      accP0 = MFMA16(A0h[i], b0, accP0);
      accP1 = MFMA16(A1h[i], b0, accP1);
      s16x8 b2 = *(const s16x8*)(W1H + row*W1STR + off);
      q0 = MFMA16(A0g[i], b2, q0);
      q1 = MFMA16(A1g[i], b2, q1);
    }
    { // two-plane partial write + single sync + per-thread sums
      float* gw = Gred + (w << 10) + row;
      #pragma unroll
      for (int v = 0; v < 4; ++v) {
        gw[(((kg<<2)+v)    << 4)]       = accP0[v];
        gw[(((kg<<2)+v+16) << 4)]       = accP1[v];
        gw[512 + (((kg<<2)+v)    << 4)] = q0[v];
        gw[512 + (((kg<<2)+v+16) << 4)] = q1[v];
      }
      __syncthreads();
      float s0 = 0.f, s1 = 0.f;
      #pragma unroll
      for (int w8 = 0; w8 < 8; ++w8) {
        s0 += Gred[(w8 << 10) + tid];
        s1 += Gred[(w8 << 10) + 512 + tid];
      }
      float a0g_ = s0;
      float b0g_ = __shfl_xor(s0, 1);
      float c0g_ = __shfl_xor(s0, 2);
      float d0g_ = __shfl_xor(b0g_, 2);
      float a1g_ = s1;
      float b1g_ = __shfl_xor(s1, 1);
      float c1g_ = __shfl_xor(s1, 2);
      float d1g_ = __shfl_xor(b1g_, 2);
      if (eg == 0) {
        // ---- LSTM1(t) epilogue -> h1(t) ----
        f32x4 bi1 = *(const f32x4*)(b1s + (ep << 2));
        float gi = a1g_ + bi1[0], gf = b1g_ + bi1[1], gg = c1g_ + bi1[2], go = d1g_ + bi1[3];
        float cn1 = sigmf(gf) * c1l[ep*32 + eb] + sigmf(gi) * tanhf(gg);
        c1l[ep*32 + eb] = cn1;
        float hn1 = sigmf(go) * tanhf(cn1);
        // ---- LSTM0(t+1) epilogue -> h0(t+1) ----
        f32x4 bi0 = *(const f32x4*)(b0s + (ep << 2));
        float fi = a0g_ + bi0[0], ff = b0g_ + bi0[1], fg = c0g_ + bi0[2], fo = d0g_ + bi0[3];
        float cn0 = sigmf(ff) * c0l[ep*32 + eb] + sigmf(fi) * tanhf(fg);
        c0l[ep*32 + eb] = cn0;
        float hn0 = sigmf(fo) * tanhf(cn0);
        float h1B = __shfl_xor(hn1, 4);
        float h1C = __shfl_xor(hn1, 8);
        float h1D = __shfl_xor(h1B, 8);
        float h0B = __shfl_xor(hn0, 4);
        float h0C = __shfl_xor(hn0, 8);
        float h0D = __shfl_xor(h0B, 8);
        if ((tid & 15) == 0) {
          u64 hp1 = (u64)f2bf(hn1) | ((u64)f2bf(h1B) << 16) | ((u64)f2bf(h1C) << 32) | ((u64)f2bf(h1D) << 48);
          st64a(h1W + (cblk << 10) + (eb << 5) + colw, hp1);
          u64 hp0 = (u64)f2bf(hn0) | ((u64)f2bf(h0B) << 16) | ((u64)f2bf(h0C) << 32) | ((u64)f2bf(h0D) << 48);
          st64a(h0Wn + (cblk << 10) + (eb << 5) + colw, hp0);
        }
      }
    }
    // ===== publish: all stores drained, then post both chunk flags =====
    __builtin_amdgcn_s_waitcnt(0);
    __syncthreads();
    if (tid == 0) {
      __hip_atomic_fetch_add(flg + ((size_t)(t+1)*32 + cblk)*4, 1u, __ATOMIC_RELAXED, __HIP_MEMORY_SCOPE_AGENT);
      __hip_atomic_fetch_add(flg + H1OFFU + ((size_t)t*32 + cblk)*4, 1u, __ATOMIC_RELAXED, __HIP_MEMORY_SCOPE_AGENT);
    }

    // ===== window: static(t+2) MFMAs only (FC deferred) =====
    accP0 = z4; accP1 = z4;
    if (t + 2 < TT)
      mfma_static(xstat + (size_t)(t+2)*BBAT*KS, W0, w, row, kg, accP0, accP1);
  }

  // ===== deferred FC: all h1 published; grid.sync fences -> plain cached loads =====
  grid.sync();
  {
    const int g2 = tid >> 3, l = tid & 7;       // 64 groups of 8 lanes
    for (int tt = blk; tt < TT; tt += NBLK) {
      const unsigned short* hh = h1h + (size_t)(tt+1)*BBAT*HH;   // h1(tt)
      for (int pass = 0; pass < 40; ++pass) {
        const int idx = pass*64 + g2;           // 0..2559 = 32b x 80m
        const int b = idx / MM, m = idx - b*MM;
        float pp = 0.f;
        #pragma unroll
        for (int ci = 0; ci < 4; ++ci) {
          const int c = (l << 2) + ci;
          const unsigned short* hp = hh + (c << 10) + (b << 5);
          const float* wp = Wfc + (size_t)m*HH + (c << 5);
          #pragma unroll
          for (int q = 0; q < 8; ++q) {
            u64 hq = *(const u64*)(hp + (q << 2));
            float4 wv = *(const float4*)(wp + (q << 2));
            pp = fmaf(bf2f((unsigned short)hq), wv.x,
                 fmaf(bf2f((unsigned short)(hq >> 16)), wv.y,
                 fmaf(bf2f((unsigned short)(hq >> 32)), wv.z,
                 fmaf(bf2f((unsigned short)(hq >> 48)), wv.w, pp))));
          }
        }
        pp += __shfl_down(pp, 4);
        pp += __shfl_down(pp, 2);
        pp += __shfl_down(pp, 1);
        if (l == 0) out[((size_t)b*TT + tt)*MM + m] = pp + bfc[m];
      }
    }
  }
}

extern "C" void kernel_launch(void* const* d_in, const int* in_sizes, int n_in,
                              void* d_out, int out_size, void* d_ws, size_t ws_size,
                              hipStream_t stream) {
  const float* enc  = (const float*)d_in[0];
  const float* audio= (const float*)d_in[1];
  const float* Wih0 = (const float*)d_in[2];
  const float* Whh0 = (const float*)d_in[3];
  const float* bih0 = (const float*)d_in[4];
  const float* bhh0 = (const float*)d_in[5];
  const float* Wih1 = (const float*)d_in[6];
  const float* Whh1 = (const float*)d_in[7];
  const float* bih1 = (const float*)d_in[8];
  const float* bhh1 = (const float*)d_in[9];
  const float* Wa   = (const float*)d_in[10];
  const float* ba   = (const float*)d_in[11];
  const float* Wfc  = (const float*)d_in[12];
  const float* bfc  = (const float*)d_in[13];
  float* out = (float*)d_out;
  float* ws  = (float*)d_ws;

  (void)hipFuncSetAttribute((const void*)decoder_kernel,
                            hipFuncAttributeMaxDynamicSharedMemorySize, LDS_TOTAL);

  void* args[] = { &enc,&audio,&Wih0,&Whh0,&bih0,&bhh0,&Wih1,&Whh1,&bih1,&bhh1,
                   &Wa,&ba,&Wfc,&bfc,&out,&ws };
  hipLaunchCooperativeKernel((const void*)decoder_kernel, dim3(NBLK), dim3(NTHR),
                             args, LDS_TOTAL, stream);
}

// Round 19
// 2798.756 us; speedup vs baseline: 1.1688x; 1.1688x over previous
//
#include <hip/hip_runtime.h>
#include <hip/hip_cooperative_groups.h>

namespace cg = cooperative_groups;

#define BBAT 32
#define SE 200
#define TT 400
#define MM 80
#define EE 512
#define HH 1024
#define IN0 592
#define KS 608         // static panel row: x(80) + ctx(512) + zero pad(16)
#define NSC 19         // static chunks (KS/32)
#define W0S 1640       // W0 LDS row stride (608 static + 1024 hh + 8 pad)
#define W1STR 1032
#define NBLK 256
#define NTHR 512

typedef __attribute__((ext_vector_type(4))) float f32x4;
typedef __attribute__((ext_vector_type(8))) short s16x8;
typedef unsigned long long u64;

// LDS offsets (bytes)
#define OFF_W0    0          // 16*1640*2 = 52480
#define OFF_W1I   52480      // 33024
#define OFF_W1H   85504      // 33024
#define OFF_GRED  118528     // 8 waves x 1024 f32 = 32768 (2 planes)
#define OFF_C0    151296     // 512
#define OFF_C1    151808     // 512
#define OFF_BS    152320     // b0s[16] + b1s[16] f32 = 128
#define LDS_TOTAL 152448
// prologue-only smw/red alias the GRED region (no temporal overlap)

// ws offsets (bytes)
// h0b/h1b are CHUNK-MAJOR: [2 parity][32 chunk][32 batch][32 elem] bf16
#define WS_XSTAT 0                 // 400*32*608*2 = 15,564,800
#define WS_H0B   15564800          // 131,072
#define WS_H1B   15695872          // 131,072
#define WS_H1F   15826944          // 3*32*1024*4 = 393,216 (triple buffer, [b][k] f32)
#define WS_ESC   16220160          // 25,600
#define WS_CST   16245760          // 131,072 (cm | cs)
#define WS_FLG   16376832          // merged flags: (TT+1)*32 x 16B = 205,312
// flag epoch e chunk c -> flg[(e*32+c)*4]; epoch e == {h0(e), h1(e-1)} published
#define FLGN     ((TT+1)*32*4)

__device__ __forceinline__ float sigmf(float x){ return 1.0f/(1.0f+expf(-x)); }

__device__ __forceinline__ unsigned short f2bf(float v){
  unsigned int u = __float_as_uint(v);
  u += 0x7fffu + ((u >> 16) & 1u);
  return (unsigned short)(u >> 16);
}

// ---- agent-scope coherent accessors; RELAXED => no cache-maintenance ops ----
__device__ __forceinline__ void st64a(void* p, u64 v){
  __hip_atomic_store((u64*)p, v, __ATOMIC_RELAXED, __HIP_MEMORY_SCOPE_AGENT);
}
__device__ __forceinline__ u64 ld64a(const void* p){
  return __hip_atomic_load((const u64*)p, __ATOMIC_RELAXED, __HIP_MEMORY_SCOPE_AGENT);
}
__device__ __forceinline__ float2 ld2f(const float* p){
  u64 q = ld64a(p);
  float2 r; r.x = __uint_as_float((unsigned)q); r.y = __uint_as_float((unsigned)(q >> 32));
  return r;
}
__device__ __forceinline__ u64 pk2f(float a, float b){
  return ((u64)__float_as_uint(b) << 32) | (u64)__float_as_uint(a);
}

// 4x 16B coherent loads (sc0 sc1 -> coherence point). Chunk-major: each wave
// spans 1KB contiguous per instruction (8x128B lines).
#define LD4C(d0,d1,d2,d3,p0,p1,p2,p3) \
  asm volatile("global_load_dwordx4 %0, %4, off sc0 sc1\n\t" \
               "global_load_dwordx4 %1, %5, off sc0 sc1\n\t" \
               "global_load_dwordx4 %2, %6, off sc0 sc1\n\t" \
               "global_load_dwordx4 %3, %7, off sc0 sc1" \
               : "=&v"(d0), "=&v"(d1), "=&v"(d2), "=&v"(d3) \
               : "v"(p0), "v"(p1), "v"(p2), "v"(p3))

// Single waitcnt tying all 16 fragments as in-outs (anti-hoist: rule #18).
#define WAIT16(a0,a1,a2,a3,b0,b1,b2,b3,c0,c1,c2,c3,d0,d1,d2,d3) \
  asm volatile("s_waitcnt vmcnt(0)" \
    : "+v"(a0),"+v"(a1),"+v"(a2),"+v"(a3), \
      "+v"(b0),"+v"(b1),"+v"(b2),"+v"(b3), \
      "+v"(c0),"+v"(c1),"+v"(c2),"+v"(c3), \
      "+v"(d0),"+v"(d1),"+v"(d2),"+v"(d3))

__device__ __forceinline__ float bsum(float v, float* red){
  #pragma unroll
  for (int o = 32; o; o >>= 1) v += __shfl_down(v, o);
  __syncthreads();
  if ((threadIdx.x & 63) == 0) red[threadIdx.x >> 6] = v;
  __syncthreads();
  float s = 0.f;
  #pragma unroll
  for (int w2 = 0; w2 < 8; ++w2) s += red[w2];
  return s;
}
__device__ __forceinline__ float bmax(float v, float* red){
  #pragma unroll
  for (int o = 32; o; o >>= 1) v = fmaxf(v, __shfl_down(v, o));
  __syncthreads();
  if ((threadIdx.x & 63) == 0) red[threadIdx.x >> 6] = v;
  __syncthreads();
  float s = -3.4e38f;
  #pragma unroll
  for (int w2 = 0; w2 < 8; ++w2) s = fmaxf(s, red[w2]);
  return s;
}

#define MFMA16(a,b,c) __builtin_amdgcn_mfma_f32_16x16x32_bf16((a),(b),(c),0,0,0)

// static-panel MFMAs for LSTM0 time tau (cached loads; xstat stable after prologue)
__device__ __forceinline__ void mfma_static(const unsigned short* __restrict__ xs,
    const unsigned short* __restrict__ W0, int w, int row, int kg,
    f32x4& acc0, f32x4& acc1)
{
  for (int c = w; c < NSC; c += 8) {
    const int off = (c << 5) + (kg << 3);
    s16x8 a0 = *(const s16x8*)(xs + (size_t)row*KS + off);
    s16x8 a1 = *(const s16x8*)(xs + (size_t)(row+16)*KS + off);
    s16x8 bw = *(const s16x8*)(W0 + row*W0S + off);
    acc0 = MFMA16(a0, bw, acc0);
    acc1 = MFMA16(a1, bw, acc1);
  }
}

__global__ void __launch_bounds__(NTHR, 1) decoder_kernel(
    const float* __restrict__ enc, const float* __restrict__ audio,
    const float* __restrict__ Wih0, const float* __restrict__ Whh0,
    const float* __restrict__ bih0, const float* __restrict__ bhh0,
    const float* __restrict__ Wih1, const float* __restrict__ Whh1,
    const float* __restrict__ bih1, const float* __restrict__ bhh1,
    const float* __restrict__ Wa, const float* __restrict__ ba,
    const float* __restrict__ Wfc, const float* __restrict__ bfc,
    float* __restrict__ out, float* __restrict__ ws)
{
  cg::grid_group grid = cg::this_grid();
  extern __shared__ char lds[];
  unsigned short* W0  = (unsigned short*)(lds + OFF_W0);
  unsigned short* W1I = (unsigned short*)(lds + OFF_W1I);
  unsigned short* W1H = (unsigned short*)(lds + OFF_W1H);
  float* Gred = (float*)(lds + OFF_GRED);
  float* c0l  = (float*)(lds + OFF_C0);
  float* c1l  = (float*)(lds + OFF_C1);
  float* b0s  = (float*)(lds + OFF_BS);      // combined LSTM0 biases [p*4+g]
  float* b1s  = b0s + 16;                    // combined LSTM1 biases
  float* smw  = Gred;                        // prologue-only aliases
  float* red  = Gred + 256;

  const int blk = blockIdx.x, tid = threadIdx.x;
  const int j = blk;                                // owns h-columns [4j, 4j+4)
  const int w = tid >> 6, lane = tid & 63;
  const int row = lane & 15, kg = lane >> 4;
  const int cblk = j >> 3;                          // chunk holding this block's cols
  const int colw = (j & 7) << 2;                    // col offset within chunk
  const int eg = tid & 3, ep = (tid >> 2) & 3, eb = tid >> 4;

  unsigned short* xstat = (unsigned short*)((char*)ws + WS_XSTAT);
  unsigned short* h0b   = (unsigned short*)((char*)ws + WS_H0B);   // chunk-major
  unsigned short* h1b   = (unsigned short*)((char*)ws + WS_H1B);   // chunk-major
  float* h1f  = (float*)((char*)ws + WS_H1F);       // 3 parity buffers, [b][k]
  float* esc  = (float*)((char*)ws + WS_ESC);
  float* cm   = (float*)((char*)ws + WS_CST);
  float* cs   = cm + BBAT*EE;
  unsigned* flg = (unsigned*)((char*)ws + WS_FLG);  // merged dataflow flags

  // ---- prologue: weights -> LDS bf16; combined biases ----
  for (int i = tid; i < 16*W0S; i += NTHR) {
    int r = i / W0S, k = i - r*W0S;
    int n = (r & 3)*HH + 4*j + (r >> 2);
    float v = 0.f;
    if (k < IN0) v = Wih0[(size_t)n*IN0 + k];
    else if (k >= KS && k < KS + HH) v = Whh0[(size_t)n*HH + (k - KS)];
    W0[i] = f2bf(v);
  }
  for (int i = tid; i < 16*W1STR; i += NTHR) {
    int r = i / W1STR, k = i - r*W1STR;
    int n = (r & 3)*HH + 4*j + (r >> 2);
    W1I[i] = (k < HH) ? f2bf(Wih1[(size_t)n*HH + k]) : (unsigned short)0;
    W1H[i] = (k < HH) ? f2bf(Whh1[(size_t)n*HH + k]) : (unsigned short)0;
  }
  if (tid < 16) {
    int p = tid >> 2, g = tid & 3, n = g*HH + 4*j + p;
    b0s[tid] = bih0[n] + bhh0[n];
    b1s[tid] = bih1[n] + bhh1[n];
  }
  if (tid < 128) { c0l[tid] = 0.f; c1l[tid] = 0.f; }
  for (int i = blk*NTHR + tid; i < 2*BBAT*HH; i += NBLK*NTHR) { h0b[i] = 0; h1b[i] = 0; }
  for (int i = blk*NTHR + tid; i < 3*BBAT*HH; i += NBLK*NTHR) h1f[i] = 0.f;
  for (int i = blk*NTHR + tid; i < FLGN; i += NBLK*NTHR) flg[i] = 0u;
  for (int r2 = blk; r2 < BBAT*SE; r2 += NBLK) {
    float pp = tanhf(enc[(size_t)r2*EE + tid]) * Wa[HH + tid];   // EE == NTHR
    pp = bsum(pp, red);
    if (tid == 0) esc[r2] = pp;
  }
  grid.sync();

  // ---- static softmax + contexts (softmax is h1-invariant; R10-R18 validated) ----
  if (blk < BBAT) {
    const int b = blk;
    float sc = (tid < SE) ? esc[b*SE + tid] : -3.4e38f;
    float mx = bmax(sc, red);
    float ex = (tid < SE) ? expf(sc - mx) : 0.f;
    float den = bsum(ex, red);
    if (tid < SE) smw[tid] = ex / den;
    __syncthreads();
    const int e = tid;                                // EE == NTHR
    float as = 0.f, am = 0.f;
    for (int s = 0; s < SE; ++s) {
      float v = enc[((size_t)b*SE + s)*EE + e];
      as = fmaf(smw[s], v, as);
      am += v;
    }
    cm[b*EE + e] = am * (1.0f/(float)SE);
    cs[b*EE + e] = as;
  }
  grid.sync();

  // ---- fill static panel xstat[t][b][608] = [x_t | ctx | 0] bf16 ----
  for (int t2 = blk; t2 < TT; t2 += NBLK) {
    const float* cx = (t2 == 0) ? cm : cs;
    for (int b = 0; b < BBAT; ++b) {
      for (int k = tid; k < KS; k += NTHR) {
        float v;
        if (k < MM)        v = audio[((size_t)b*TT + t2)*MM + k];
        else if (k < IN0)  v = cx[b*EE + (k - MM)];
        else               v = 0.f;
        xstat[((size_t)t2*BBAT + b)*KS + k] = f2bf(v);
      }
    }
  }
  grid.sync();   // covers flag zeroing + xstat + initial h-buffers

  const f32x4 z4 = {0.f,0.f,0.f,0.f};
  f32x4 accP0 = z4, accP1 = z4;

  // ---- pre-loop: LSTM0(0) = static(0) (h0(-1)=0); publish h0(0) + epoch-0 flag ----
  mfma_static(xstat, W0, w, row, kg, accP0, accP1);
  {
    float* gw = Gred + (w << 10) + row;
    #pragma unroll
    for (int v = 0; v < 4; ++v) {
      gw[(((kg<<2)+v)    << 4)] = accP0[v];
      gw[(((kg<<2)+v+16) << 4)] = accP1[v];
    }
    __syncthreads();
    float s0 = 0.f;
    #pragma unroll
    for (int w8 = 0; w8 < 8; ++w8) s0 += Gred[(w8 << 10) + tid];
    float ga = s0;
    float gb = __shfl_xor(s0, 1);
    float gc = __shfl_xor(s0, 2);
    float gd = __shfl_xor(gb, 2);
    if (eg == 0) {
      f32x4 bi = *(const f32x4*)(b0s + (ep << 2));
      float gi = ga + bi[0], gg = gc + bi[2], go = gd + bi[3];
      float cn = sigmf(gi) * tanhf(gg);   // c_old = 0
      c0l[ep*32 + eb] = cn;
      float hn = sigmf(go) * tanhf(cn);
      float hB = __shfl_xor(hn, 4);
      float hC = __shfl_xor(hn, 8);
      float hD = __shfl_xor(hB, 8);
      if ((tid & 15) == 0) {
        u64 hp = (u64)f2bf(hn) | ((u64)f2bf(hB) << 16) | ((u64)f2bf(hC) << 32) | ((u64)f2bf(hD) << 48);
        st64a(h0b + (cblk << 10) + (eb << 5) + colw, hp);   // h0(0) -> parity buf 0
      }
    }
  }
  __builtin_amdgcn_s_waitcnt(0);
  __syncthreads();
  if (tid == 0)
    __hip_atomic_fetch_add(flg + (size_t)cblk*4, 1u, __ATOMIC_RELAXED, __HIP_MEMORY_SCOPE_AGENT);
  accP0 = z4; accP1 = z4;
  mfma_static(xstat + (size_t)BBAT*KS, W0, w, row, kg, accP0, accP1);  // static(1)

  int s1w = 0;                       // h1f write slot = t % 3
  for (int t = 0; t < TT; ++t) {
    const int s1r = (s1w == 0) ? 2 : s1w - 1;                  // (t-1) % 3
    const unsigned short* h0R = h0b + (t&1)*BBAT*HH;           // h0(t), chunk-major
    const unsigned short* h1R = h1b + ((t&1)^1)*BBAT*HH;       // h1(t-1)
    unsigned short* h1W = h1b + (t&1)*BBAT*HH;                 // h1(t)
    unsigned short* h0Wn = h0b + ((t+1)&1)*BBAT*HH;            // h0(t+1)
    float* h1fW = h1f + (size_t)s1w*BBAT*HH;

    // ===== per-wave dataflow poll: epoch t covers h0(t) AND h1(t-1) =====
    {
      const int pc = w + ((lane & 3) << 3);
      if (lane < 4) {
        unsigned* fp = flg + ((size_t)t*32 + pc)*4;
        while (__hip_atomic_load(fp, __ATOMIC_RELAXED, __HIP_MEMORY_SCOPE_AGENT) < 8u)
          __builtin_amdgcn_s_sleep(1);
      }
      asm volatile("" ::: "memory");   // loads below must not hoist above polls
    }

    // ===== coalesced coherent loads, 40 MFMA, reduce, shfl epilogues =====
    s16x8 A0h[4], A1h[4], A0g[4], A1g[4];
    {
      const unsigned short* ph0a  = h0R + (row << 5) + (kg << 3);
      const unsigned short* ph0b_ = h0R + ((row+16) << 5) + (kg << 3);
      const unsigned short* ph1a  = h1R + (row << 5) + (kg << 3);
      const unsigned short* ph1b_ = h1R + ((row+16) << 5) + (kg << 3);
      const int o0 = (w << 10), o1 = ((w+8) << 10), o2_ = ((w+16) << 10), o3 = ((w+24) << 10);
      LD4C(A0h[0],A0h[1],A0h[2],A0h[3], ph0a+o0, ph0a+o1, ph0a+o2_, ph0a+o3);
      LD4C(A1h[0],A1h[1],A1h[2],A1h[3], ph0b_+o0, ph0b_+o1, ph0b_+o2_, ph0b_+o3);
      LD4C(A0g[0],A0g[1],A0g[2],A0g[3], ph1a+o0, ph1a+o1, ph1a+o2_, ph1a+o3);
      LD4C(A1g[0],A1g[1],A1g[2],A1g[3], ph1b_+o0, ph1b_+o1, ph1b_+o2_, ph1b_+o3);
      WAIT16(A0h[0],A0h[1],A0h[2],A0h[3], A1h[0],A1h[1],A1h[2],A1h[3],
             A0g[0],A0g[1],A0g[2],A0g[3], A1g[0],A1g[1],A1g[2],A1g[3]);
    }
    f32x4 q0 = z4, q1 = z4;
    #pragma unroll
    for (int i = 0; i < 4; ++i) {
      const int off = ((w + (i << 3)) << 5) + (kg << 3);
      s16x8 b1 = *(const s16x8*)(W1I + row*W1STR + off);
      q0 = MFMA16(A0h[i], b1, q0);
      q1 = MFMA16(A1h[i], b1, q1);
      s16x8 b0 = *(const s16x8*)(W0 + row*W0S + KS + off);
      accP0 = MFMA16(A0h[i], b0, accP0);
      accP1 = MFMA16(A1h[i], b0, accP1);
      s16x8 b2 = *(const s16x8*)(W1H + row*W1STR + off);
      q0 = MFMA16(A0g[i], b2, q0);
      q1 = MFMA16(A1g[i], b2, q1);
    }
    { // two-plane partial write + single sync + per-thread sums
      float* gw = Gred + (w << 10) + row;
      #pragma unroll
      for (int v = 0; v < 4; ++v) {
        gw[(((kg<<2)+v)    << 4)]       = accP0[v];
        gw[(((kg<<2)+v+16) << 4)]       = accP1[v];
        gw[512 + (((kg<<2)+v)    << 4)] = q0[v];
        gw[512 + (((kg<<2)+v+16) << 4)] = q1[v];
      }
      __syncthreads();   // also aggregates all waves' polls: all 32 chunks observed
      float s0 = 0.f, s1 = 0.f;
      #pragma unroll
      for (int w8 = 0; w8 < 8; ++w8) {
        s0 += Gred[(w8 << 10) + tid];
        s1 += Gred[(w8 << 10) + 512 + tid];
      }
      float a0g_ = s0;
      float b0g_ = __shfl_xor(s0, 1);
      float c0g_ = __shfl_xor(s0, 2);
      float d0g_ = __shfl_xor(b0g_, 2);
      float a1g_ = s1;
      float b1g_ = __shfl_xor(s1, 1);
      float c1g_ = __shfl_xor(s1, 2);
      float d1g_ = __shfl_xor(b1g_, 2);
      if (eg == 0) {
        // ---- LSTM1(t) epilogue -> h1(t) ----
        f32x4 bi1 = *(const f32x4*)(b1s + (ep << 2));
        float gi = a1g_ + bi1[0], gf = b1g_ + bi1[1], gg = c1g_ + bi1[2], go = d1g_ + bi1[3];
        float cn1 = sigmf(gf) * c1l[ep*32 + eb] + sigmf(gi) * tanhf(gg);
        c1l[ep*32 + eb] = cn1;
        float hn1 = sigmf(go) * tanhf(cn1);
        // ---- LSTM0(t+1) epilogue -> h0(t+1) ----
        f32x4 bi0 = *(const f32x4*)(b0s + (ep << 2));
        float fi = a0g_ + bi0[0], ff = b0g_ + bi0[1], fg = c0g_ + bi0[2], fo = d0g_ + bi0[3];
        float cn0 = sigmf(ff) * c0l[ep*32 + eb] + sigmf(fi) * tanhf(fg);
        c0l[ep*32 + eb] = cn0;
        float hn0 = sigmf(fo) * tanhf(cn0);
        float h1B = __shfl_xor(hn1, 4);
        float h1C = __shfl_xor(hn1, 8);
        float h1D = __shfl_xor(h1B, 8);
        float h0B = __shfl_xor(hn0, 4);
        float h0C = __shfl_xor(hn0, 8);
        float h0D = __shfl_xor(h0B, 8);
        if ((tid & 15) == 0) {
          u64 hp1 = (u64)f2bf(hn1) | ((u64)f2bf(h1B) << 16) | ((u64)f2bf(h1C) << 32) | ((u64)f2bf(h1D) << 48);
          st64a(h1W + (cblk << 10) + (eb << 5) + colw, hp1);
          st64a(h1fW + (size_t)eb*HH + 4*j,     pk2f(hn1, h1B));
          st64a(h1fW + (size_t)eb*HH + 4*j + 2, pk2f(h1C, h1D));
          u64 hp0 = (u64)f2bf(hn0) | ((u64)f2bf(h0B) << 16) | ((u64)f2bf(h0C) << 32) | ((u64)f2bf(h0D) << 48);
          st64a(h0Wn + (cblk << 10) + (eb << 5) + colw, hp0);
        }
      }
    }
    // ===== publish: all stores drained, then ONE merged epoch flag =====
    __builtin_amdgcn_s_waitcnt(0);
    __syncthreads();
    if (tid == 0)
      __hip_atomic_fetch_add(flg + ((size_t)(t+1)*32 + cblk)*4, 1u, __ATOMIC_RELAXED, __HIP_MEMORY_SCOPE_AGENT);

    // ===== window: FC pred(t-1), then static(t+2) =====
    if (t >= 1) {   // h1f(t-1): all chunks observed at this step's aggregated polls
      const float* h1fF = h1f + (size_t)s1r*BBAT*HH;
      for (int u = w; u < 10; u += 8) {
        int idx = j*10 + u;
        int b = idx / MM, m = idx - b*MM;
        float pp = 0.f;
        #pragma unroll
        for (int cq = 0; cq < 4; ++cq) {
          float2 h0v = ld2f(h1fF + (size_t)b*HH + cq*256 + lane*4);
          float2 h1v = ld2f(h1fF + (size_t)b*HH + cq*256 + lane*4 + 2);
          float4 wv = *(const float4*)(Wfc + (size_t)m*HH + cq*256 + lane*4);
          pp = fmaf(h0v.x,wv.x, fmaf(h0v.y,wv.y, fmaf(h1v.x,wv.z, fmaf(h1v.y,wv.w, pp))));
        }
        #pragma unroll
        for (int o2 = 32; o2; o2 >>= 1) pp += __shfl_down(pp, o2);
        if (lane == 0) out[((size_t)b*TT + (t-1))*MM + m] = pp + bfc[m];
      }
    }
    accP0 = z4; accP1 = z4;
    if (t + 2 < TT)
      mfma_static(xstat + (size_t)(t+2)*BBAT*KS, W0, w, row, kg, accP0, accP1);
    s1w = (s1w == 2) ? 0 : s1w + 1;
  }

  // ---- final: wait for epoch TT (h1(TT-1) published), then FC pred(TT-1) ----
  if (tid < 32) {
    unsigned* fp = flg + ((size_t)TT*32 + tid)*4;
    while (__hip_atomic_load(fp, __ATOMIC_RELAXED, __HIP_MEMORY_SCOPE_AGENT) < 8u)
      __builtin_amdgcn_s_sleep(1);
  }
  __syncthreads();
  {
    const float* h1fL = h1f + (size_t)((TT-1) % 3)*BBAT*HH;
    for (int u = w; u < 10; u += 8) {
      int idx = j*10 + u;
      int b = idx / MM, m = idx - b*MM;
      float pp = 0.f;
      #pragma unroll
      for (int cq = 0; cq < 4; ++cq) {
        float2 h0v = ld2f(h1fL + (size_t)b*HH + cq*256 + lane*4);
        float2 h1v = ld2f(h1fL + (size_t)b*HH + cq*256 + lane*4 + 2);
        float4 wv = *(const float4*)(Wfc + (size_t)m*HH + cq*256 + lane*4);
        pp = fmaf(h0v.x,wv.x, fmaf(h0v.y,wv.y, fmaf(h1v.x,wv.z, fmaf(h1v.y,wv.w, pp))));
      }
      #pragma unroll
      for (int o2 = 32; o2; o2 >>= 1) pp += __shfl_down(pp, o2);
      if (lane == 0) out[((size_t)b*TT + (TT-1))*MM + m] = pp + bfc[m];
    }
  }
}

extern "C" void kernel_launch(void* const* d_in, const int* in_sizes, int n_in,
                              void* d_out, int out_size, void* d_ws, size_t ws_size,
                              hipStream_t stream) {
  const float* enc  = (const float*)d_in[0];
  const float* audio= (const float*)d_in[1];
  const float* Wih0 = (const float*)d_in[2];
  const float* Whh0 = (const float*)d_in[3];
  const float* bih0 = (const float*)d_in[4];
  const float* bhh0 = (const float*)d_in[5];
  const float* Wih1 = (const float*)d_in[6];
  const float* Whh1 = (const float*)d_in[7];
  const float* bih1 = (const float*)d_in[8];
  const float* bhh1 = (const float*)d_in[9];
  const float* Wa   = (const float*)d_in[10];
  const float* ba   = (const float*)d_in[11];
  const float* Wfc  = (const float*)d_in[12];
  const float* bfc  = (const float*)d_in[13];
  float* out = (float*)d_out;
  float* ws  = (float*)d_ws;

  (void)hipFuncSetAttribute((const void*)decoder_kernel,
                            hipFuncAttributeMaxDynamicSharedMemorySize, LDS_TOTAL);

  void* args[] = { &enc,&audio,&Wih0,&Whh0,&bih0,&bhh0,&Wih1,&Whh1,&bih1,&bhh1,
                   &Wa,&ba,&Wfc,&bfc,&out,&ws };
  hipLaunchCooperativeKernel((const void*)decoder_kernel, dim3(NBLK), dim3(NTHR),
                             args, LDS_TOTAL, stream);
}